// Round 8
// baseline (632.746 us; speedup 1.0000x reference)
//
#include <hip/hip_runtime.h>
#include <cstdint>
#include <cstddef>

typedef __attribute__((ext_vector_type(8))) short short8;
typedef __attribute__((ext_vector_type(4))) float f32x4;

// ---- bf16 helpers (RN, pure bit ops) ----
__device__ __forceinline__ unsigned short f32_to_bf16_rn(float f) {
  unsigned int u = __float_as_uint(f);
  u += 0x7FFFu + ((u >> 16) & 1u);
  return (unsigned short)(u >> 16);
}
__device__ __forceinline__ float bf16_to_f32(unsigned short b) {
  return __uint_as_float(((unsigned int)b) << 16);
}
__device__ __forceinline__ float4 bf4_to_f4(ushort4 v) {
  float4 r;
  r.x = bf16_to_f32(v.x); r.y = bf16_to_f32(v.y);
  r.z = bf16_to_f32(v.z); r.w = bf16_to_f32(v.w);
  return r;
}

// direct global->LDS 16B async copy; LDS dest = wave-uniform base + lane*16
__device__ __forceinline__ void gload16(const void* g, const void* l) {
  __builtin_amdgcn_global_load_lds(
      (const __attribute__((address_space(1))) unsigned int*)g,
      (__attribute__((address_space(3))) unsigned int*)l, 16, 0, 0);
}

// ---------------- fused prep: count-atomics | xcast | wtrans x3 ----------------
// blocks [0,1024): degree histogram; [1024,3072): x->bf16; [3072,3584): W1^T;
// [3584,3840): W2^T; [3840,4096): W3^T.  (independent streams, overlap on GPU)
__global__ __launch_bounds__(256) void k_prep(
    const int* __restrict__ dst, int* __restrict__ cnt, int E,
    const float* __restrict__ x, unsigned short* __restrict__ xh, int nx4,
    const float* __restrict__ W1, unsigned short* __restrict__ WT1,
    const float* __restrict__ W2, unsigned short* __restrict__ WT2,
    const float* __restrict__ W3, unsigned short* __restrict__ WT3) {
  int b = blockIdx.x;
  if (b < 1024) {
    int i = b * 256 + threadIdx.x;
    for (int e = i; e < E; e += 1024 * 256) atomicAdd(&cnt[dst[e]], 1);
  } else if (b < 3072) {
    for (int i = (b - 1024) * 256 + threadIdx.x; i < nx4; i += 2048 * 256) {
      float4 v = ((const float4*)x)[i];
      ushort4 h;
      h.x = f32_to_bf16_rn(v.x); h.y = f32_to_bf16_rn(v.y);
      h.z = f32_to_bf16_rn(v.z); h.w = f32_to_bf16_rn(v.w);
      ((ushort4*)xh)[i] = h;
    }
  } else if (b < 3584) {
    int idx = (b - 3072) * 256 + threadIdx.x;  // 131072 = 256 n x 512 k
    int n = idx >> 9, k = idx & 511;
    WT1[(size_t)n * 512 + k] = f32_to_bf16_rn(W1[(size_t)k * 256 + n]);
  } else if (b < 3840) {
    int idx = (b - 3584) * 256 + threadIdx.x;  // 65536
    int n = idx >> 8, k = idx & 255;
    WT2[(size_t)n * 256 + k] = f32_to_bf16_rn(W2[(size_t)k * 256 + n]);
  } else {
    int idx = (b - 3840) * 256 + threadIdx.x;
    int n = idx >> 8, k = idx & 255;
    WT3[(size_t)n * 256 + k] = f32_to_bf16_rn(W3[(size_t)k * 256 + n]);
  }
}

// ---------------- scan1 (+ fused dinv) ----------------
__global__ void k_scan1(const int* __restrict__ cnt, float* __restrict__ dinv,
                        int* __restrict__ excl, int* __restrict__ bsum, int M) {
  __shared__ int s[256];
  int gid = blockIdx.x * 256 + threadIdx.x;
  int v = (gid < M) ? cnt[gid] : 0;
  if (gid < M) dinv[gid] = rsqrtf((float)(v + 1));  // +1 self loop
  s[threadIdx.x] = v;
  __syncthreads();
  for (int off = 1; off < 256; off <<= 1) {
    int t = (threadIdx.x >= off) ? s[threadIdx.x - off] : 0;
    __syncthreads();
    s[threadIdx.x] += t;
    __syncthreads();
  }
  if (gid < M) excl[gid] = s[threadIdx.x] - v;
  if (threadIdx.x == 255) bsum[blockIdx.x] = s[255];
}

__global__ void k_scan2(int* bsum, int nb) {
  __shared__ int s[256];
  int v = (threadIdx.x < nb) ? bsum[threadIdx.x] : 0;
  s[threadIdx.x] = v;
  __syncthreads();
  for (int off = 1; off < 256; off <<= 1) {
    int t = (threadIdx.x >= off) ? s[threadIdx.x - off] : 0;
    __syncthreads();
    s[threadIdx.x] += t;
    __syncthreads();
  }
  if (threadIdx.x < nb) bsum[threadIdx.x] = s[threadIdx.x] - v;  // exclusive
}

// finalize row_ptr and init cursor = row_ptr (so scatter needs no row_ptr read)
__global__ void k_scan3(int* __restrict__ row_ptr, int* __restrict__ cursor,
                        const int* __restrict__ bsum, int M, int E) {
  int gid = blockIdx.x * 256 + threadIdx.x;
  if (gid < M) {
    int v = row_ptr[gid] + bsum[blockIdx.x];
    row_ptr[gid] = v;
    cursor[gid] = v;
  }
  if (gid == 0) row_ptr[M] = E;
}

// ---------------- CSR scatter (cursor pre-seeded with row starts) ----------------
__global__ void k_scatter(const int* __restrict__ src, const int* __restrict__ dst,
                          int* __restrict__ cursor, int* __restrict__ eidx, int E) {
  int i = blockIdx.x * blockDim.x + threadIdx.x;
  for (int e = i; e < E; e += gridDim.x * blockDim.x) {
    int pos = atomicAdd(&cursor[dst[e]], 1);
    eidx[pos] = src[e];
  }
}

// ---------------- pure-bf16 MFMA GEMM, 2-phase dbuf + counted vmcnt ----------------
// outbf[r, 0:256] = bf16( (A[r,0:K] @ W[0:K,0:256]) * dinv[r] ),  A,WT bf16
#define BM 64
#define BN 256
#define BK 32

__global__ __launch_bounds__(256, 3) void k_gemm(
    const unsigned short* __restrict__ A, const unsigned short* __restrict__ WT,
    const float* __restrict__ dinv, unsigned short* __restrict__ out, int M, int K) {
  // per buffer: A [0,4K) | B [4K,20K); double buffered (40 KB total -> 3 blocks/CU)
  constexpr int BUFB = 20480;
  __shared__ __align__(16) char lds[2 * BUFB];
  const int tid = threadIdx.x;
  const int lane = tid & 63;
  const int wv = tid >> 6;  // wave -> col block wv*64
  const int row0 = blockIdx.x * BM;

  // 20 chunks of 1KB per buffer: 0..3 = A, 4..19 = B. Wave w owns {w+4i}.
  // Source 16B-slot XOR-preswizzled (involution) so linear LDS + same-XOR
  // ds_read is <=2-way per 16-lane group (G21 both-sides pairing).
  const char* gsrc[5];
  unsigned ldsoff[5];
#pragma unroll
  for (int i = 0; i < 5; ++i) {
    int c = wv + 4 * i;
    ldsoff[i] = (unsigned)(c * 1024);
    if (c < 4) {  // A rows c*16 .. c*16+15 (64B per row)
      int r = c * 16 + (lane >> 2);
      int sslot = (lane & 3) ^ ((r >> 1) & 3);
      int gr = row0 + r; gr = gr < M ? gr : (M - 1);  // clamp (no HW masking)
      gsrc[i] = (const char*)(A + (size_t)gr * K + sslot * 8);
    } else {  // B cols (c-4)*16 .. +15
      int col = (c - 4) * 16 + (lane >> 2);
      int sslot = (lane & 3) ^ ((col >> 1) & 3);
      gsrc[i] = (const char*)(WT + (size_t)col * K + sslot * 8);
    }
  }

  f32x4 acc[4][4] = {};  // [m][n]
  const int fr = lane & 15;
  const int ks = lane >> 4;  // k-slot 0..3
  const int NT = K / BK;     // 16 (L1) or 8 (L2/3), always even

  // prologue: stage tile 0 -> buffer 0
#pragma unroll
  for (int i = 0; i < 5; ++i) { gload16(gsrc[i], lds + ldsoff[i]); gsrc[i] += 64; }

  auto phase = [&](int curo, int nxto, bool dostage) {
    if (dostage) {  // next tile's 5 loads stay in flight across this MFMA phase
#pragma unroll
      for (int i = 0; i < 5; ++i) { gload16(gsrc[i], lds + nxto + ldsoff[i]); gsrc[i] += 64; }
      asm volatile("s_waitcnt vmcnt(5)" ::: "memory");  // drain only cur tile's loads
    } else {
      asm volatile("s_waitcnt vmcnt(0)" ::: "memory");
    }
    __builtin_amdgcn_s_barrier();        // cur buffer staged in all waves
    __builtin_amdgcn_sched_barrier(0);   // don't hoist ds_reads above (rule 18)

    short8 ah[4];
#pragma unroll
    for (int m = 0; m < 4; ++m) {
      int rr = m * 16 + fr;
      int so = (ks ^ ((rr >> 1) & 3)) * 16;
      ah[m] = *(const short8*)&lds[curo + rr * 64 + so];
    }
#pragma unroll
    for (int n = 0; n < 4; ++n) {
      int cc = wv * 64 + n * 16 + fr;
      int so = (ks ^ ((cc >> 1) & 3)) * 16;
      short8 bh = *(const short8*)&lds[curo + 4096 + cc * 64 + so];
#pragma unroll
      for (int m = 0; m < 4; ++m)
        acc[m][n] = __builtin_amdgcn_mfma_f32_16x16x32_bf16(ah[m], bh, acc[m][n], 0, 0, 0);
    }
    __builtin_amdgcn_sched_barrier(0);
    __builtin_amdgcn_s_barrier();  // all waves done reading before overwrite
  };

  for (int t = 0; t < NT; t += 2) {
    phase(0, BUFB, true);        // read buf0, stage buf1
    phase(BUFB, 0, t + 2 < NT);  // read buf1, stage buf0
  }

  // epilogue: C/D layout col=lane&15, row=(lane>>4)*4+reg (m89-verified)
  const int rq = (lane >> 4) * 4;
#pragma unroll
  for (int m = 0; m < 4; ++m) {
#pragma unroll
    for (int r = 0; r < 4; ++r) {
      int gr = row0 + m * 16 + rq + r;
      if (gr < M) {
        float s = dinv[gr];
#pragma unroll
        for (int n = 0; n < 4; ++n)
          out[(size_t)gr * BN + wv * 64 + n * 16 + fr] = f32_to_bf16_rn(acc[m][n][r] * s);
      }
    }
  }
}

// ---------------- aggregate: h[i] = bf16(relu(dinv[i]*(hws[i]+sum hws[src]) + b)) ----
__global__ __launch_bounds__(64) void k_aggregate(
    const unsigned short* __restrict__ hws, const int* __restrict__ eidx,
    const int* __restrict__ row_ptr, const float* __restrict__ dinv,
    const float* __restrict__ bias, unsigned short* __restrict__ outp, int M) {
  int i = blockIdx.x;
  if (i >= M) return;
  int t = threadIdx.x;  // 64 threads x 4 feats = 256
  float4 acc = bf4_to_f4(*(const ushort4*)(hws + (size_t)i * 256 + t * 4));  // self loop
  int e = row_ptr[i], end = row_ptr[i + 1];
  for (; e + 8 <= end; e += 8) {  // 8 row-gathers in flight
    int s0 = eidx[e], s1 = eidx[e + 1], s2 = eidx[e + 2], s3 = eidx[e + 3];
    int s4 = eidx[e + 4], s5 = eidx[e + 5], s6 = eidx[e + 6], s7 = eidx[e + 7];
    ushort4 v0 = *(const ushort4*)(hws + (size_t)s0 * 256 + t * 4);
    ushort4 v1 = *(const ushort4*)(hws + (size_t)s1 * 256 + t * 4);
    ushort4 v2 = *(const ushort4*)(hws + (size_t)s2 * 256 + t * 4);
    ushort4 v3 = *(const ushort4*)(hws + (size_t)s3 * 256 + t * 4);
    ushort4 v4 = *(const ushort4*)(hws + (size_t)s4 * 256 + t * 4);
    ushort4 v5 = *(const ushort4*)(hws + (size_t)s5 * 256 + t * 4);
    ushort4 v6 = *(const ushort4*)(hws + (size_t)s6 * 256 + t * 4);
    ushort4 v7 = *(const ushort4*)(hws + (size_t)s7 * 256 + t * 4);
    float4 f0 = bf4_to_f4(v0), f1 = bf4_to_f4(v1), f2 = bf4_to_f4(v2), f3 = bf4_to_f4(v3);
    float4 f4 = bf4_to_f4(v4), f5 = bf4_to_f4(v5), f6 = bf4_to_f4(v6), f7 = bf4_to_f4(v7);
    acc.x += ((f0.x + f1.x) + (f2.x + f3.x)) + ((f4.x + f5.x) + (f6.x + f7.x));
    acc.y += ((f0.y + f1.y) + (f2.y + f3.y)) + ((f4.y + f5.y) + (f6.y + f7.y));
    acc.z += ((f0.z + f1.z) + (f2.z + f3.z)) + ((f4.z + f5.z) + (f6.z + f7.z));
    acc.w += ((f0.w + f1.w) + (f2.w + f3.w)) + ((f4.w + f5.w) + (f6.w + f7.w));
  }
  for (; e < end; ++e) {
    int s = eidx[e];
    float4 v = bf4_to_f4(*(const ushort4*)(hws + (size_t)s * 256 + t * 4));
    acc.x += v.x; acc.y += v.y; acc.z += v.z; acc.w += v.w;
  }
  float d = dinv[i];
  float4 b = *(const float4*)(bias + t * 4);
  ushort4 o;
  o.x = f32_to_bf16_rn(fmaxf(fmaf(acc.x, d, b.x), 0.f));
  o.y = f32_to_bf16_rn(fmaxf(fmaf(acc.y, d, b.y), 0.f));
  o.z = f32_to_bf16_rn(fmaxf(fmaf(acc.z, d, b.z), 0.f));
  o.w = f32_to_bf16_rn(fmaxf(fmaf(acc.w, d, b.w), 0.f));
  *(ushort4*)(outp + (size_t)i * 256 + t * 4) = o;
}

// ---------------- fused pool + classify (batch sorted -> contiguous ranges) --------
__global__ __launch_bounds__(256) void k_poolclass(
    const unsigned short* __restrict__ h, const float* __restrict__ Wl,
    const float* __restrict__ bl, float* __restrict__ out, int M, int G) {
  __shared__ float sg[256];
  __shared__ float logits[10];
  int b = blockIdx.x;
  int t = threadIdx.x;
  // graph b owns nodes [ceil(b*M/G), ceil((b+1)*M/G))
  long s = ((long)b * M + G - 1) / G;
  long e = ((long)(b + 1) * M + G - 1) / G;
  if (e > M) e = M;
  float mx = 0.f;  // post-relu values >= 0, segments non-empty
  for (long n = s; n < e; ++n) mx = fmaxf(mx, bf16_to_f32(h[n * 256 + t]));
  sg[t] = mx;
  __syncthreads();
  if (t < 10) {
    float sum = bl[t];
    for (int k = 0; k < 256; ++k) sum = fmaf(sg[k], Wl[k * 10 + t], sum);
    logits[t] = sum;
  }
  __syncthreads();
  if (t == 0) {
    float m = logits[0];
    for (int c = 1; c < 10; c++) m = fmaxf(m, logits[c]);
    float sum = 0.f;
    for (int c = 0; c < 10; c++) sum += expf(logits[c] - m);
    float lse = m + logf(sum);
    for (int c = 0; c < 10; c++) out[b * 10 + c] = logits[c] - lse;
  }
}

static inline size_t align256(size_t x) { return (x + 255) & ~(size_t)255; }

extern "C" void kernel_launch(void* const* d_in, const int* in_sizes, int n_in,
                              void* d_out, int out_size, void* d_ws, size_t ws_size,
                              hipStream_t stream) {
  const float* x   = (const float*)d_in[0];
  const int*   ei  = (const int*)d_in[1];
  const float* W1  = (const float*)d_in[3];
  const float* b1  = (const float*)d_in[4];
  const float* W2  = (const float*)d_in[5];
  const float* b2  = (const float*)d_in[6];
  const float* W3  = (const float*)d_in[7];
  const float* b3  = (const float*)d_in[8];
  const float* Wl  = (const float*)d_in[9];
  const float* bl  = (const float*)d_in[10];
  float* out = (float*)d_out;

  const int M = in_sizes[0] / 512;  // 50000
  const int E = in_sizes[1] / 2;    // 800000
  const int G = out_size / 10;      // 64
  const int K1 = 512, H = 256;

  const int* src = ei;
  const int* dst = ei + E;

  char* p = (char*)d_ws;
  size_t off = 0;
  float* p_dinv = (float*)(p + off); off = align256(off + (size_t)M * 4);
  int* cnt      = (int*)(p + off);   off = align256(off + (size_t)M * 4);
  int* cursor   = (int*)(p + off);   off = align256(off + (size_t)M * 4);
  int* row_ptr  = (int*)(p + off);   off = align256(off + ((size_t)M + 1) * 4);
  int* bsum     = (int*)(p + off);   off = align256(off + 256 * 4);
  int* eidx     = (int*)(p + off);   off = align256(off + (size_t)E * 4);
  unsigned short* WT1 = (unsigned short*)(p + off); off = align256(off + (size_t)H * K1 * 2);
  unsigned short* WT2 = (unsigned short*)(p + off); off = align256(off + (size_t)H * H * 2);
  unsigned short* WT3 = (unsigned short*)(p + off); off = align256(off + (size_t)H * H * 2);
  unsigned short* xh  = (unsigned short*)(p + off); off = align256(off + (size_t)M * K1 * 2);
  unsigned short* hws = (unsigned short*)(p + off); off = align256(off + (size_t)M * H * 2);
  unsigned short* h   = (unsigned short*)(p + off); off = align256(off + (size_t)M * H * 2);
  (void)ws_size;

  int nb = (M + 255) / 256;  // 196

  hipMemsetAsync(cnt, 0, (size_t)M * 4, stream);
  k_prep<<<4096, 256, 0, stream>>>(dst, cnt, E, x, xh, M * K1 / 4,
                                   W1, WT1, W2, WT2, W3, WT3);
  k_scan1<<<nb, 256, 0, stream>>>(cnt, p_dinv, row_ptr, bsum, M);
  k_scan2<<<1, 256, 0, stream>>>(bsum, nb);
  k_scan3<<<nb, 256, 0, stream>>>(row_ptr, cursor, bsum, M, E);
  k_scatter<<<1024, 256, 0, stream>>>(src, dst, cursor, eidx, E);

  int gblk = (M + BM - 1) / BM;
  // layer 1 (K=512)
  k_gemm<<<gblk, 256, 0, stream>>>(xh, WT1, p_dinv, hws, M, K1);
  k_aggregate<<<M, 64, 0, stream>>>(hws, eidx, row_ptr, p_dinv, b1, h, M);
  // layer 2
  k_gemm<<<gblk, 256, 0, stream>>>(h, WT2, p_dinv, hws, M, H);
  k_aggregate<<<M, 64, 0, stream>>>(hws, eidx, row_ptr, p_dinv, b2, h, M);
  // layer 3
  k_gemm<<<gblk, 256, 0, stream>>>(h, WT3, p_dinv, hws, M, H);
  k_aggregate<<<M, 64, 0, stream>>>(hws, eidx, row_ptr, p_dinv, b3, h, M);

  k_poolclass<<<G, 256, 0, stream>>>(h, Wl, bl, out, M, G);
}

// Round 13
// 539.447 us; speedup vs baseline: 1.1730x; 1.1730x over previous
//
#include <hip/hip_runtime.h>
#include <cstdint>
#include <cstddef>

typedef __attribute__((ext_vector_type(8))) short short8;
typedef __attribute__((ext_vector_type(4))) float f32x4;

// ---- bf16 helpers (RN, pure bit ops) ----
__device__ __forceinline__ unsigned short f32_to_bf16_rn(float f) {
  unsigned int u = __float_as_uint(f);
  u += 0x7FFFu + ((u >> 16) & 1u);
  return (unsigned short)(u >> 16);
}
__device__ __forceinline__ float bf16_to_f32(unsigned short b) {
  return __uint_as_float(((unsigned int)b) << 16);
}
__device__ __forceinline__ float4 bf4_to_f4(ushort4 v) {
  float4 r;
  r.x = bf16_to_f32(v.x); r.y = bf16_to_f32(v.y);
  r.z = bf16_to_f32(v.z); r.w = bf16_to_f32(v.w);
  return r;
}

// direct global->LDS 16B async copy; LDS dest = wave-uniform base + lane*16
__device__ __forceinline__ void gload16(const void* g, const void* l) {
  __builtin_amdgcn_global_load_lds(
      (const __attribute__((address_space(1))) unsigned int*)g,
      (__attribute__((address_space(3))) unsigned int*)l, 16, 0, 0);
}

// ---------------- fused prep: count-atomics | xcast | wtrans x3 ----------------
__global__ __launch_bounds__(256) void k_prep(
    const int* __restrict__ dst, int* __restrict__ cnt, int E,
    const float* __restrict__ x, unsigned short* __restrict__ xh, int nx4,
    const float* __restrict__ W1, unsigned short* __restrict__ WT1,
    const float* __restrict__ W2, unsigned short* __restrict__ WT2,
    const float* __restrict__ W3, unsigned short* __restrict__ WT3) {
  int b = blockIdx.x;
  if (b < 1024) {
    int i = b * 256 + threadIdx.x;
    for (int e = i; e < E; e += 1024 * 256) atomicAdd(&cnt[dst[e]], 1);
  } else if (b < 3072) {
    for (int i = (b - 1024) * 256 + threadIdx.x; i < nx4; i += 2048 * 256) {
      float4 v = ((const float4*)x)[i];
      ushort4 h;
      h.x = f32_to_bf16_rn(v.x); h.y = f32_to_bf16_rn(v.y);
      h.z = f32_to_bf16_rn(v.z); h.w = f32_to_bf16_rn(v.w);
      ((ushort4*)xh)[i] = h;
    }
  } else if (b < 3584) {
    int idx = (b - 3072) * 256 + threadIdx.x;  // 131072 = 256 n x 512 k
    int n = idx >> 9, k = idx & 511;
    WT1[(size_t)n * 512 + k] = f32_to_bf16_rn(W1[(size_t)k * 256 + n]);
  } else if (b < 3840) {
    int idx = (b - 3584) * 256 + threadIdx.x;  // 65536
    int n = idx >> 8, k = idx & 255;
    WT2[(size_t)n * 256 + k] = f32_to_bf16_rn(W2[(size_t)k * 256 + n]);
  } else {
    int idx = (b - 3840) * 256 + threadIdx.x;
    int n = idx >> 8, k = idx & 255;
    WT3[(size_t)n * 256 + k] = f32_to_bf16_rn(W3[(size_t)k * 256 + n]);
  }
}

// ---------------- scan1 (+ fused dinv) ----------------
__global__ void k_scan1(const int* __restrict__ cnt, float* __restrict__ dinv,
                        int* __restrict__ excl, int* __restrict__ bsum, int M) {
  __shared__ int s[256];
  int gid = blockIdx.x * 256 + threadIdx.x;
  int v = (gid < M) ? cnt[gid] : 0;
  if (gid < M) dinv[gid] = rsqrtf((float)(v + 1));  // +1 self loop
  s[threadIdx.x] = v;
  __syncthreads();
  for (int off = 1; off < 256; off <<= 1) {
    int t = (threadIdx.x >= off) ? s[threadIdx.x - off] : 0;
    __syncthreads();
    s[threadIdx.x] += t;
    __syncthreads();
  }
  if (gid < M) excl[gid] = s[threadIdx.x] - v;
  if (threadIdx.x == 255) bsum[blockIdx.x] = s[255];
}

__global__ void k_scan2(int* bsum, int nb) {
  __shared__ int s[256];
  int v = (threadIdx.x < nb) ? bsum[threadIdx.x] : 0;
  s[threadIdx.x] = v;
  __syncthreads();
  for (int off = 1; off < 256; off <<= 1) {
    int t = (threadIdx.x >= off) ? s[threadIdx.x - off] : 0;
    __syncthreads();
    s[threadIdx.x] += t;
    __syncthreads();
  }
  if (threadIdx.x < nb) bsum[threadIdx.x] = s[threadIdx.x] - v;  // exclusive
}

// finalize row_ptr and init cursor = row_ptr (so scatter needs no row_ptr read)
__global__ void k_scan3(int* __restrict__ row_ptr, int* __restrict__ cursor,
                        const int* __restrict__ bsum, int M, int E) {
  int gid = blockIdx.x * 256 + threadIdx.x;
  if (gid < M) {
    int v = row_ptr[gid] + bsum[blockIdx.x];
    row_ptr[gid] = v;
    cursor[gid] = v;
  }
  if (gid == 0) row_ptr[M] = E;
}

// ---------------- CSR scatter (cursor pre-seeded with row starts) ----------------
__global__ void k_scatter(const int* __restrict__ src, const int* __restrict__ dst,
                          int* __restrict__ cursor, int* __restrict__ eidx, int E) {
  int i = blockIdx.x * blockDim.x + threadIdx.x;
  for (int e = i; e < E; e += gridDim.x * blockDim.x) {
    int pos = atomicAdd(&cursor[dst[e]], 1);
    eidx[pos] = src[e];
  }
}

// ---------------- pure-bf16 MFMA GEMM, 2-phase dbuf + counted vmcnt ----------------
// outbf[r, 0:256] = bf16( (A[r,0:K] @ W[0:K,0:256]) * dinv[r] ),  A,WT bf16
#define BM 64
#define BN 256
#define BK 32

__global__ __launch_bounds__(256, 3) void k_gemm(
    const unsigned short* __restrict__ A, const unsigned short* __restrict__ WT,
    const float* __restrict__ dinv, unsigned short* __restrict__ out, int M, int K) {
  // per buffer: A [0,4K) | B [4K,20K); double buffered (40 KB total -> 3 blocks/CU)
  constexpr int BUFB = 20480;
  __shared__ __align__(16) char lds[2 * BUFB];
  const int tid = threadIdx.x;
  const int lane = tid & 63;
  const int wv = tid >> 6;  // wave -> col block wv*64
  const int row0 = blockIdx.x * BM;

  // 20 chunks of 1KB per buffer: 0..3 = A, 4..19 = B. Wave w owns {w+4i}.
  // Source 16B-slot XOR-preswizzled (involution) so linear LDS + same-XOR
  // ds_read is <=2-way per 16-lane group (G21 both-sides pairing).
  const char* gsrc[5];
  unsigned ldsoff[5];
#pragma unroll
  for (int i = 0; i < 5; ++i) {
    int c = wv + 4 * i;
    ldsoff[i] = (unsigned)(c * 1024);
    if (c < 4) {  // A rows c*16 .. c*16+15 (64B per row)
      int r = c * 16 + (lane >> 2);
      int sslot = (lane & 3) ^ ((r >> 1) & 3);
      int gr = row0 + r; gr = gr < M ? gr : (M - 1);  // clamp (no HW masking)
      gsrc[i] = (const char*)(A + (size_t)gr * K + sslot * 8);
    } else {  // B cols (c-4)*16 .. +15
      int col = (c - 4) * 16 + (lane >> 2);
      int sslot = (lane & 3) ^ ((col >> 1) & 3);
      gsrc[i] = (const char*)(WT + (size_t)col * K + sslot * 8);
    }
  }

  f32x4 acc[4][4] = {};  // [m][n]
  const int fr = lane & 15;
  const int ks = lane >> 4;  // k-slot 0..3
  const int NT = K / BK;     // 16 (L1) or 8 (L2/3), always even

  // prologue: stage tile 0 -> buffer 0
#pragma unroll
  for (int i = 0; i < 5; ++i) { gload16(gsrc[i], lds + ldsoff[i]); gsrc[i] += 64; }

  auto phase = [&](int curo, int nxto, bool dostage) {
    if (dostage) {  // next tile's 5 loads stay in flight across this MFMA phase
#pragma unroll
      for (int i = 0; i < 5; ++i) { gload16(gsrc[i], lds + nxto + ldsoff[i]); gsrc[i] += 64; }
      asm volatile("s_waitcnt vmcnt(5)" ::: "memory");  // drain only cur tile's loads
    } else {
      asm volatile("s_waitcnt vmcnt(0)" ::: "memory");
    }
    __builtin_amdgcn_s_barrier();        // cur buffer staged in all waves
    __builtin_amdgcn_sched_barrier(0);   // don't hoist ds_reads above (rule 18)

    short8 ah[4];
#pragma unroll
    for (int m = 0; m < 4; ++m) {
      int rr = m * 16 + fr;
      int so = (ks ^ ((rr >> 1) & 3)) * 16;
      ah[m] = *(const short8*)&lds[curo + rr * 64 + so];
    }
#pragma unroll
    for (int n = 0; n < 4; ++n) {
      int cc = wv * 64 + n * 16 + fr;
      int so = (ks ^ ((cc >> 1) & 3)) * 16;
      short8 bh = *(const short8*)&lds[curo + 4096 + cc * 64 + so];
#pragma unroll
      for (int m = 0; m < 4; ++m)
        acc[m][n] = __builtin_amdgcn_mfma_f32_16x16x32_bf16(ah[m], bh, acc[m][n], 0, 0, 0);
    }
    __builtin_amdgcn_sched_barrier(0);
    __builtin_amdgcn_s_barrier();  // all waves done reading before overwrite
  };

  for (int t = 0; t < NT; t += 2) {
    phase(0, BUFB, true);        // read buf0, stage buf1
    phase(BUFB, 0, t + 2 < NT);  // read buf1, stage buf0
  }

  // epilogue: C/D layout col=lane&15, row=(lane>>4)*4+reg (m89-verified)
  const int rq = (lane >> 4) * 4;
#pragma unroll
  for (int m = 0; m < 4; ++m) {
#pragma unroll
    for (int r = 0; r < 4; ++r) {
      int gr = row0 + m * 16 + rq + r;
      if (gr < M) {
        float s = dinv[gr];
#pragma unroll
        for (int n = 0; n < 4; ++n)
          out[(size_t)gr * BN + wv * 64 + n * 16 + fr] = f32_to_bf16_rn(acc[m][n][r] * s);
      }
    }
  }
}

// ---------------- aggregate: h[i] = bf16(relu(dinv[i]*(hws[i]+sum hws[src]) + b))
// 256-thread blocks = 4 independent waves, 1 node each (occupancy: 32 waves/CU) ----
__global__ __launch_bounds__(256) void k_aggregate(
    const unsigned short* __restrict__ hws, const int* __restrict__ eidx,
    const int* __restrict__ row_ptr, const float* __restrict__ dinv,
    const float* __restrict__ bias, unsigned short* __restrict__ outp, int M) {
  int i = blockIdx.x * 4 + (threadIdx.x >> 6);
  if (i >= M) return;
  int t = threadIdx.x & 63;  // 64 lanes x 4 feats = 256
  float4 acc = bf4_to_f4(*(const ushort4*)(hws + (size_t)i * 256 + t * 4));  // self loop
  int e = row_ptr[i], end = row_ptr[i + 1];
  for (; e + 8 <= end; e += 8) {  // 8 row-gathers in flight
    int s0 = eidx[e], s1 = eidx[e + 1], s2 = eidx[e + 2], s3 = eidx[e + 3];
    int s4 = eidx[e + 4], s5 = eidx[e + 5], s6 = eidx[e + 6], s7 = eidx[e + 7];
    ushort4 v0 = *(const ushort4*)(hws + (size_t)s0 * 256 + t * 4);
    ushort4 v1 = *(const ushort4*)(hws + (size_t)s1 * 256 + t * 4);
    ushort4 v2 = *(const ushort4*)(hws + (size_t)s2 * 256 + t * 4);
    ushort4 v3 = *(const ushort4*)(hws + (size_t)s3 * 256 + t * 4);
    ushort4 v4 = *(const ushort4*)(hws + (size_t)s4 * 256 + t * 4);
    ushort4 v5 = *(const ushort4*)(hws + (size_t)s5 * 256 + t * 4);
    ushort4 v6 = *(const ushort4*)(hws + (size_t)s6 * 256 + t * 4);
    ushort4 v7 = *(const ushort4*)(hws + (size_t)s7 * 256 + t * 4);
    float4 f0 = bf4_to_f4(v0), f1 = bf4_to_f4(v1), f2 = bf4_to_f4(v2), f3 = bf4_to_f4(v3);
    float4 f4 = bf4_to_f4(v4), f5 = bf4_to_f4(v5), f6 = bf4_to_f4(v6), f7 = bf4_to_f4(v7);
    acc.x += ((f0.x + f1.x) + (f2.x + f3.x)) + ((f4.x + f5.x) + (f6.x + f7.x));
    acc.y += ((f0.y + f1.y) + (f2.y + f3.y)) + ((f4.y + f5.y) + (f6.y + f7.y));
    acc.z += ((f0.z + f1.z) + (f2.z + f3.z)) + ((f4.z + f5.z) + (f6.z + f7.z));
    acc.w += ((f0.w + f1.w) + (f2.w + f3.w)) + ((f4.w + f5.w) + (f6.w + f7.w));
  }
  for (; e < end; ++e) {
    int s = eidx[e];
    float4 v = bf4_to_f4(*(const ushort4*)(hws + (size_t)s * 256 + t * 4));
    acc.x += v.x; acc.y += v.y; acc.z += v.z; acc.w += v.w;
  }
  float d = dinv[i];
  float4 b = *(const float4*)(bias + t * 4);
  ushort4 o;
  o.x = f32_to_bf16_rn(fmaxf(fmaf(acc.x, d, b.x), 0.f));
  o.y = f32_to_bf16_rn(fmaxf(fmaf(acc.y, d, b.y), 0.f));
  o.z = f32_to_bf16_rn(fmaxf(fmaf(acc.z, d, b.z), 0.f));
  o.w = f32_to_bf16_rn(fmaxf(fmaf(acc.w, d, b.w), 0.f));
  *(ushort4*)(outp + (size_t)i * 256 + t * 4) = o;
}

// ---------------- segment max pool (batch sorted; h bf16; g zero-initialized) ------
__global__ __launch_bounds__(256) void k_pool(const unsigned short* __restrict__ h,
                                              const int* __restrict__ batch,
                                              float* __restrict__ g, int M) {
  int node0 = blockIdx.x * 32;
  if (node0 >= M) return;
  int t = threadIdx.x;
  int nEnd = min(node0 + 32, M);
  int cur = batch[node0];
  float acc = 0.f;  // post-relu values >= 0
  for (int n = node0; n < nEnd; ++n) {
    int b = batch[n];
    if (b != cur) {
      atomicMax((int*)&g[(size_t)cur * 256 + t], __float_as_int(acc));
      acc = 0.f; cur = b;
    }
    acc = fmaxf(acc, bf16_to_f32(h[(size_t)n * 256 + t]));
  }
  atomicMax((int*)&g[(size_t)cur * 256 + t], __float_as_int(acc));
}

// ---------------- classifier: log_softmax(g @ Wl + bl) ----------------
__global__ __launch_bounds__(256) void k_classify(const float* __restrict__ g,
                                                  const float* __restrict__ Wl,
                                                  const float* __restrict__ bl,
                                                  float* __restrict__ out) {
  __shared__ float sg[256];
  __shared__ float logits[10];
  int b = blockIdx.x;
  sg[threadIdx.x] = g[(size_t)b * 256 + threadIdx.x];
  __syncthreads();
  if (threadIdx.x < 10) {
    float s = bl[threadIdx.x];
    for (int k = 0; k < 256; ++k) s = fmaf(sg[k], Wl[k * 10 + threadIdx.x], s);
    logits[threadIdx.x] = s;
  }
  __syncthreads();
  if (threadIdx.x == 0) {
    float m = logits[0];
    for (int c = 1; c < 10; c++) m = fmaxf(m, logits[c]);
    float sum = 0.f;
    for (int c = 0; c < 10; c++) sum += expf(logits[c] - m);
    float lse = m + logf(sum);
    for (int c = 0; c < 10; c++) out[b * 10 + c] = logits[c] - lse;
  }
}

static inline size_t align256(size_t x) { return (x + 255) & ~(size_t)255; }

extern "C" void kernel_launch(void* const* d_in, const int* in_sizes, int n_in,
                              void* d_out, int out_size, void* d_ws, size_t ws_size,
                              hipStream_t stream) {
  const float* x   = (const float*)d_in[0];
  const int*   ei  = (const int*)d_in[1];
  const int*   bat = (const int*)d_in[2];
  const float* W1  = (const float*)d_in[3];
  const float* b1  = (const float*)d_in[4];
  const float* W2  = (const float*)d_in[5];
  const float* b2  = (const float*)d_in[6];
  const float* W3  = (const float*)d_in[7];
  const float* b3  = (const float*)d_in[8];
  const float* Wl  = (const float*)d_in[9];
  const float* bl  = (const float*)d_in[10];
  float* out = (float*)d_out;

  const int M = in_sizes[0] / 512;  // 50000
  const int E = in_sizes[1] / 2;    // 800000
  const int G = out_size / 10;      // 64
  const int K1 = 512, H = 256;

  const int* src = ei;
  const int* dst = ei + E;

  char* p = (char*)d_ws;
  size_t off = 0;
  float* p_dinv = (float*)(p + off); off = align256(off + (size_t)M * 4);
  int* cnt      = (int*)(p + off);   off = align256(off + (size_t)M * 4);
  int* cursor   = (int*)(p + off);   off = align256(off + (size_t)M * 4);
  int* row_ptr  = (int*)(p + off);   off = align256(off + ((size_t)M + 1) * 4);
  int* bsum     = (int*)(p + off);   off = align256(off + 256 * 4);
  float* g      = (float*)(p + off); off = align256(off + (size_t)G * H * 4);
  int* eidx     = (int*)(p + off);   off = align256(off + (size_t)E * 4);
  unsigned short* WT1 = (unsigned short*)(p + off); off = align256(off + (size_t)H * K1 * 2);
  unsigned short* WT2 = (unsigned short*)(p + off); off = align256(off + (size_t)H * H * 2);
  unsigned short* WT3 = (unsigned short*)(p + off); off = align256(off + (size_t)H * H * 2);
  unsigned short* xh  = (unsigned short*)(p + off); off = align256(off + (size_t)M * K1 * 2);
  unsigned short* hws = (unsigned short*)(p + off); off = align256(off + (size_t)M * H * 2);
  unsigned short* h   = (unsigned short*)(p + off); off = align256(off + (size_t)M * H * 2);
  (void)ws_size;

  int nb = (M + 255) / 256;  // 196

  hipMemsetAsync(cnt, 0, (size_t)M * 4, stream);
  hipMemsetAsync(g, 0, (size_t)G * H * 4, stream);
  k_prep<<<4096, 256, 0, stream>>>(dst, cnt, E, x, xh, M * K1 / 4,
                                   W1, WT1, W2, WT2, W3, WT3);
  k_scan1<<<nb, 256, 0, stream>>>(cnt, p_dinv, row_ptr, bsum, M);
  k_scan2<<<1, 256, 0, stream>>>(bsum, nb);
  k_scan3<<<nb, 256, 0, stream>>>(row_ptr, cursor, bsum, M, E);
  k_scatter<<<1024, 256, 0, stream>>>(src, dst, cursor, eidx, E);

  int gblk = (M + BM - 1) / BM;
  int ablk = (M + 3) / 4;
  // layer 1 (K=512)
  k_gemm<<<gblk, 256, 0, stream>>>(xh, WT1, p_dinv, hws, M, K1);
  k_aggregate<<<ablk, 256, 0, stream>>>(hws, eidx, row_ptr, p_dinv, b1, h, M);
  // layer 2
  k_gemm<<<gblk, 256, 0, stream>>>(h, WT2, p_dinv, hws, M, H);
  k_aggregate<<<ablk, 256, 0, stream>>>(hws, eidx, row_ptr, p_dinv, b2, h, M);
  // layer 3
  k_gemm<<<gblk, 256, 0, stream>>>(h, WT3, p_dinv, hws, M, H);
  k_aggregate<<<ablk, 256, 0, stream>>>(hws, eidx, row_ptr, p_dinv, b3, h, M);

  k_pool<<<(M + 31) / 32, 256, 0, stream>>>(h, bat, g, M);
  k_classify<<<G, 256, 0, stream>>>(g, Wl, bl, out);
}